// Round 10
// baseline (9201.292 us; speedup 1.0000x reference)
//
#include <hip/hip_runtime.h>
#include <hip/hip_bf16.h>

// b=4, n=1024, dim=512, heads=8, dhead=64, inner=512, MAX_POS=512.
// ROUND 10: inputs fp32 (proven by rounds 1-2 NaN forensics + detector),
// OUTPUT NOW WRITTEN AS FP32 (harness doc: output dtype = reference output
// dtype = float32). Pipeline = round-7 full-VALU build, dict order,
// non-transposed weights.

using bf16 = __bf16;
typedef __bf16 bf16x8 __attribute__((ext_vector_type(8)));

__device__ __forceinline__ float ld_in(const void* p, long long i, int f32) {
  return f32 ? ((const float*)p)[i] : (float)((const bf16*)p)[i];
}

__global__ __launch_bounds__(256) void k_diag(float* __restrict__ out, float v) {
  int idx = blockIdx.x * 256 + threadIdx.x;
  if (idx < 4194304) out[idx] = v;
}

// per-input dtype detector (fp32 data: bf16-view low halves ~uniform bits)
__global__ void k_detect_one(const unsigned short* __restrict__ p, int nhalf,
                             int* __restrict__ flag) {
  __shared__ int cnt;
  if (threadIdx.x == 0) cnt = 0;
  __syncthreads();
  int c = 0;
  for (int i = threadIdx.x; i < nhalf; i += 256) {
    const unsigned u = p[i];
    const unsigned e = (u >> 7) & 0xFF;
    if (e == 0xFF || (e < 64 && (u & 0x7FFF) != 0)) ++c;
  }
  atomicAdd(&cnt, c);
  __syncthreads();
  if (threadIdx.x == 0) *flag = (cnt > (nhalf >> 6)) ? 1 : 0;
}

// -------------------- prep (natural layouts, dict order) --------------------
// Wc [1024][3072]: cols [0,512)=qr, [512,1024)=qi, [1024,2048)=kv_r, [2048,3072)=kv_i.
// Rows k<512 multiply a=x[...,0]; k>=512 multiply b=x[...,1].
__global__ __launch_bounds__(256) void k_build_wc(
    const void* __restrict__ wq_r, const void* __restrict__ wq_i,
    const void* __restrict__ wkv_r, const void* __restrict__ wkv_i,
    bf16* __restrict__ wc, const int* __restrict__ flags) {
  const int fqr = flags[1], fqi = flags[2], fkr = flags[3], fki = flags[4];
  const int k = blockIdx.y;
  const int c = blockIdx.x * 256 + threadIdx.x;
  const int kk = k & 511;
  const bool hi = k >= 512;
  float v;
  if (c < 512)        v = hi ? -ld_in(wq_i, kk * 512 + c, fqi) : ld_in(wq_r, kk * 512 + c, fqr);
  else if (c < 1024)  { int cc = c - 512;  v = hi ? ld_in(wq_r, kk * 512 + cc, fqr)  : ld_in(wq_i, kk * 512 + cc, fqi); }
  else if (c < 2048)  { int cc = c - 1024; v = hi ? -ld_in(wkv_i, kk * 1024 + cc, fki) : ld_in(wkv_r, kk * 1024 + cc, fkr); }
  else                { int cc = c - 2048; v = hi ? ld_in(wkv_r, kk * 1024 + cc, fkr) : ld_in(wkv_i, kk * 1024 + cc, fki); }
  wc[(size_t)k * 3072 + c] = (bf16)v;
}

__global__ __launch_bounds__(256) void k_build_wo(
    const void* __restrict__ wo_r, const void* __restrict__ wo_i,
    bf16* __restrict__ wo, const int* __restrict__ flags) {
  const int fr = flags[5], fi = flags[6];
  const int k = blockIdx.y;
  const int c = blockIdx.x * 256 + threadIdx.x;
  const int kk = k & 511;
  const bool hi = k >= 512;
  float v;
  if (c < 512) v = hi ? -ld_in(wo_i, kk * 512 + c, fi) : ld_in(wo_r, kk * 512 + c, fr);
  else { int cc = c - 512; v = hi ? ld_in(wo_r, kk * 512 + cc, fr) : ld_in(wo_i, kk * 512 + cc, fi); }
  wo[(size_t)k * 1024 + c] = (bf16)v;
}

// Xd_b [1024][1024]: cols [0,512)=x[b,m,:,0], [512,1024)=x[b,m,:,1]
__global__ __launch_bounds__(256) void k_build_xd_b(const void* __restrict__ x, bf16* __restrict__ xd,
                                                    const int* __restrict__ flags, int b) {
  const int f = flags[0];
  int idx = blockIdx.x * 256 + threadIdx.x;
  int m = idx >> 10, k = idx & 1023;
  long long base = ((long long)b * 1024 + m) * 1024;
  long long src = (k < 512) ? (base + k * 2) : (base + (k - 512) * 2 + 1);
  xd[idx] = (bf16)ld_in(x, src, f);
}

__global__ __launch_bounds__(256) void k_build_rel(const void* __restrict__ rel, bf16* __restrict__ rel_c,
                                                   const int* __restrict__ flags) {
  const int f = flags[9];
  int idx = blockIdx.x * 256 + threadIdx.x;
  if (idx < 65600) rel_c[idx] = (bf16)ld_in(rel, idx, f);
}

// -------------------- VALU GEMM: C[M][N] = A[M][K] @ W[K][N] --------------------
// MODE 0: bf16 store to C. MODE 1: +bias, store interleaved [m][c][2] as FP32 to Cf.
template <int MODE>
__global__ __launch_bounds__(256) void k_gemm_valu(
    const bf16* __restrict__ A, const bf16* __restrict__ W,
    bf16* __restrict__ C, float* __restrict__ Cf,
    const int M, const int N, const int K,
    const void* __restrict__ bias_r, const void* __restrict__ bias_i,
    const int* __restrict__ flags) {
  __shared__ float As[64][33];
  __shared__ float Ws[32][65];
  const int tid = threadIdx.x;
  const int tx = tid & 15, ty = tid >> 4;
  const int bm = blockIdx.y * 64, bn = blockIdx.x * 64;
  float acc[4][4];
#pragma unroll
  for (int i = 0; i < 4; ++i)
#pragma unroll
    for (int j = 0; j < 4; ++j) acc[i][j] = 0.f;

  for (int k0 = 0; k0 < K; k0 += 32) {
#pragma unroll
    for (int t = tid; t < 2048; t += 256) {
      const int r = t >> 5, c = t & 31;
      As[r][c] = (float)A[(size_t)(bm + r) * K + k0 + c];
    }
#pragma unroll
    for (int t = tid; t < 2048; t += 256) {
      const int r = t >> 6, c = t & 63;
      Ws[r][c] = (float)W[(size_t)(k0 + r) * N + bn + c];
    }
    __syncthreads();
#pragma unroll
    for (int kk = 0; kk < 32; ++kk) {
      float a[4], w[4];
#pragma unroll
      for (int i = 0; i < 4; ++i) a[i] = As[ty * 4 + i][kk];
#pragma unroll
      for (int j = 0; j < 4; ++j) w[j] = Ws[kk][tx * 4 + j];
#pragma unroll
      for (int i = 0; i < 4; ++i)
#pragma unroll
        for (int j = 0; j < 4; ++j) acc[i][j] += a[i] * w[j];
    }
    __syncthreads();
  }
  int fbr = 0, fbi = 0;
  if constexpr (MODE == 1) { fbr = flags[7]; fbi = flags[8]; }
#pragma unroll
  for (int i = 0; i < 4; ++i) {
    const int m = bm + ty * 4 + i;
#pragma unroll
    for (int j = 0; j < 4; ++j) {
      const int n = bn + tx * 4 + j;
      float v = acc[i][j];
      if constexpr (MODE == 0) {
        C[(size_t)m * N + n] = (bf16)v;
      } else {
        const int c = (n < 512) ? n : n - 512;
        v += ld_in((n < 512) ? bias_r : bias_i, c, (n < 512) ? fbr : fbi);
        Cf[(size_t)m * 1024 + c * 2 + ((n < 512) ? 0 : 1)] = v;  // FP32 output
      }
    }
  }
}

// -------------------- simple fp32 attention, per batch --------------------
// C1_b row i: [0,512)=qr, [512,1024)=qi, [1024,1536)=kr, [1536,2048)=vr,
// [2048,2560)=ki, [2560,3072)=vi (head: +h*64). Grid 8192 = 8 h x 1024 i.
__global__ __launch_bounds__(256) void k_attn_simple(
    const bf16* __restrict__ C1, const bf16* __restrict__ rel, bf16* __restrict__ Oc) {
  __shared__ float qr_s[64], qi_s[64];
  __shared__ float mag_s[1024];
  __shared__ float red[256];
  const int tid = threadIdx.x;
  const int i = blockIdx.x & 1023, h = blockIdx.x >> 10;
  const size_t rowQ = (size_t)i * 3072 + h * 64;
  if (tid < 64) {
    qr_s[tid] = (float)C1[rowQ + tid];
    qi_s[tid] = (float)C1[rowQ + 512 + tid];
  }
  __syncthreads();
#pragma unroll
  for (int p = 0; p < 4; ++p) {
    const int j = p * 256 + tid;
    const size_t rowK = (size_t)j * 3072 + h * 64;
    int d0 = i - j;
    d0 = d0 < -512 ? -512 : (d0 > 512 ? 512 : d0);
    const size_t rowR = (size_t)(d0 + 512) * 64;
    float dr = 0.f, di = 0.f, gr = 0.f, gi = 0.f;
#pragma unroll
    for (int dc = 0; dc < 64; dc += 8) {
      bf16x8 kr8 = *(const bf16x8*)(C1 + rowK + 1024 + dc);
      bf16x8 ki8 = *(const bf16x8*)(C1 + rowK + 2048 + dc);
      bf16x8 r8 = *(const bf16x8*)(rel + rowR + dc);
#pragma unroll
      for (int e = 0; e < 8; ++e) {
        const float qr = qr_s[dc + e], qi = qi_s[dc + e];
        const float kr = (float)kr8[e], ki = (float)ki8[e], rv = (float)r8[e];
        dr += qr * kr - qi * ki;
        di += qr * ki + qi * kr;
        gr += qr * rv;
        gi += qi * rv;
      }
    }
    dr = 0.125f * (dr + gr);
    di = 0.125f * (di + gi);
    mag_s[j] = sqrtf(dr * dr + di * di);
  }
  __syncthreads();
  float lmax = -1e30f;
#pragma unroll
  for (int p = 0; p < 4; ++p) lmax = fmaxf(lmax, mag_s[p * 256 + tid]);
  red[tid] = lmax;
  __syncthreads();
  for (int s = 128; s > 0; s >>= 1) {
    if (tid < s) red[tid] = fmaxf(red[tid], red[tid + s]);
    __syncthreads();
  }
  const float m = red[0];
  __syncthreads();
  float lsum = 0.f;
#pragma unroll
  for (int p = 0; p < 4; ++p) {
    const float e = __expf(mag_s[p * 256 + tid] - m);
    mag_s[p * 256 + tid] = e;
    lsum += e;
  }
  red[tid] = lsum;
  __syncthreads();
  for (int s = 128; s > 0; s >>= 1) {
    if (tid < s) red[tid] += red[tid + s];
    __syncthreads();
  }
  const float inv = 1.0f / red[0];
  __syncthreads();
  if (tid < 128) {
    const int d = tid & 63, ri = tid >> 6;
    const size_t colV = 1536 + (size_t)ri * 1024 + h * 64 + d;  // ri=0: vr, ri=1: vi
    float acc = 0.f;
    for (int j = 0; j < 1024; ++j)
      acc += mag_s[j] * (float)C1[(size_t)j * 3072 + colV];
    Oc[(size_t)i * 1024 + ri * 512 + h * 64 + d] = (bf16)(acc * inv);
  }
}

// -------------------- launch --------------------
extern "C" void kernel_launch(void* const* d_in, const int* in_sizes, int n_in,
                              void* d_out, int out_size, void* d_ws, size_t ws_size,
                              hipStream_t stream) {
  float* out = (float*)d_out;

  if (n_in != 10) {
    k_diag<<<16384, 256, 0, stream>>>(out, 300000.f + (float)n_in * 4096.f);
    return;
  }
  if (out_size != 4194304) {
    k_diag<<<16384, 256, 0, stream>>>(out, 400000.f);
    return;
  }
  static const int dict_sizes[10] = {4194304, 262144, 262144, 524288, 524288,
                                     262144, 262144, 512, 512, 65600};
  for (int i = 0; i < 10; ++i) {
    if (in_sizes[i] != dict_sizes[i]) {
      k_diag<<<16384, 256, 0, stream>>>(out, 200000.f);
      return;
    }
  }
  const size_t NEED = 19005696;
  if (ws_size < NEED) {
    k_diag<<<16384, 256, 0, stream>>>(out, 100000.f);
    return;
  }

  const void* x     = d_in[0];
  const void* wq_r  = d_in[1];
  const void* wq_i  = d_in[2];
  const void* wkv_r = d_in[3];
  const void* wkv_i = d_in[4];
  const void* wo_r  = d_in[5];
  const void* wo_i  = d_in[6];
  const void* bo_r  = d_in[7];
  const void* bo_i  = d_in[8];
  const void* rel   = d_in[9];

  char* ws = (char*)d_ws;
  bf16* Wc   = (bf16*)(ws);                // [1024][3072]
  bf16* Wo   = (bf16*)(ws + 6291456);      // [1024][1024]
  bf16* relc = (bf16*)(ws + 8388608);      // [1025][64]
  int*  flags= (int*)(ws + 8519808);       // 10 ints
  bf16* Xd   = (bf16*)(ws + 8519936);      // [1024][1024]
  bf16* C1   = (bf16*)(ws + 10617088);     // [1024][3072]
  bf16* Oc   = (bf16*)(ws + 16908544);     // [1024][1024] -> end 19005696

  const void* logical[10] = {x, wq_r, wq_i, wkv_r, wkv_i, wo_r, wo_i, bo_r, bo_i, rel};
  for (int i = 0; i < 10; ++i) {
    int nhalf = dict_sizes[i] < 65536 ? dict_sizes[i] : 65536;
    k_detect_one<<<1, 256, 0, stream>>>((const unsigned short*)logical[i], nhalf, flags + i);
  }

  k_build_wc<<<dim3(12, 1024), 256, 0, stream>>>(wq_r, wq_i, wkv_r, wkv_i, Wc, flags);
  k_build_wo<<<dim3(4, 1024), 256, 0, stream>>>(wo_r, wo_i, Wo, flags);
  k_build_rel<<<257, 256, 0, stream>>>(rel, relc, flags);

  for (int b = 0; b < 4; ++b) {
    k_build_xd_b<<<4096, 256, 0, stream>>>(x, Xd, flags, b);
    k_gemm_valu<0><<<dim3(48, 16), 256, 0, stream>>>(Xd, Wc, C1, nullptr, 1024, 3072, 1024,
                                                     nullptr, nullptr, flags);
    k_attn_simple<<<8192, 256, 0, stream>>>(C1, relc, Oc);
    k_gemm_valu<1><<<dim3(16, 16), 256, 0, stream>>>(Oc, Wo, nullptr, out + (size_t)b * 1048576,
                                                     1024, 1024, 1024, bo_r, bo_i, flags);
  }
}

// Round 11
// 675.911 us; speedup vs baseline: 13.6132x; 13.6132x over previous
//
#include <hip/hip_runtime.h>
#include <hip/hip_bf16.h>

// b=4, n=1024, dim=512, heads=8, dhead=64, inner=512, MAX_POS=512.
// Inputs fp32 (flag-detected, robust to bf16 too). OUTPUT = FP32.
// ROUND 11: reinstated round-3 MFMA pipeline (proven bitwise-equal to the
// VALU reference in rounds 3-5) with the fp32 output epilogue.

using bf16 = __bf16;
typedef __bf16 bf16x8 __attribute__((ext_vector_type(8)));
typedef float f32x4 __attribute__((ext_vector_type(4)));

#define MFMA16(a, b, c) __builtin_amdgcn_mfma_f32_16x16x32_bf16((a), (b), (c), 0, 0, 0)

__device__ __forceinline__ float ld_in(const void* p, long long i, int f32) {
  return f32 ? ((const float*)p)[i] : (float)((const bf16*)p)[i];
}

__global__ __launch_bounds__(256) void k_diag(float* __restrict__ out, float v) {
  int idx = blockIdx.x * 256 + threadIdx.x;
  if (idx < 4194304) out[idx] = v;
}

__global__ void k_detect_one(const unsigned short* __restrict__ p, int nhalf,
                             int* __restrict__ flag) {
  __shared__ int cnt;
  if (threadIdx.x == 0) cnt = 0;
  __syncthreads();
  int c = 0;
  for (int i = threadIdx.x; i < nhalf; i += 256) {
    const unsigned u = p[i];
    const unsigned e = (u >> 7) & 0xFF;
    if (e == 0xFF || (e < 64 && (u & 0x7FFF) != 0)) ++c;
  }
  atomicAdd(&cnt, c);
  __syncthreads();
  if (threadIdx.x == 0) *flag = (cnt > (nhalf >> 6)) ? 1 : 0;
}

// -------------------- prep: transposed (N-major) weight operands --------------------
// WcT [3072][1024]: row c: [0,512)=qr, [512,1024)=qi, [1024,2048)=kvr, [2048,3072)=kvi
__global__ __launch_bounds__(256) void k_build_wct(
    const void* __restrict__ wq_r, const void* __restrict__ wq_i,
    const void* __restrict__ wkv_r, const void* __restrict__ wkv_i,
    bf16* __restrict__ wct, const int* __restrict__ flags) {
  const int fqr = flags[1], fqi = flags[2], fkr = flags[3], fki = flags[4];
  int idx = blockIdx.x * 256 + threadIdx.x;  // 3072*1024
  int c = idx >> 10, k = idx & 1023;
  int kk = k & 511;
  bool hi = k >= 512;
  float v;
  if (c < 512)        v = hi ? -ld_in(wq_i, kk * 512 + c, fqi) : ld_in(wq_r, kk * 512 + c, fqr);
  else if (c < 1024)  { int cc = c - 512;  v = hi ? ld_in(wq_r, kk * 512 + cc, fqr)  : ld_in(wq_i, kk * 512 + cc, fqi); }
  else if (c < 2048)  { int cc = c - 1024; v = hi ? -ld_in(wkv_i, kk * 1024 + cc, fki) : ld_in(wkv_r, kk * 1024 + cc, fkr); }
  else                { int cc = c - 2048; v = hi ? ld_in(wkv_r, kk * 1024 + cc, fkr) : ld_in(wkv_i, kk * 1024 + cc, fki); }
  wct[idx] = (bf16)v;
}

// WoT [1024][1024]: row n: [0,512)=real outs, [512,1024)=imag outs
__global__ __launch_bounds__(256) void k_build_wot(
    const void* __restrict__ wo_r, const void* __restrict__ wo_i,
    bf16* __restrict__ wot, const int* __restrict__ flags) {
  const int fr = flags[5], fi = flags[6];
  int idx = blockIdx.x * 256 + threadIdx.x;  // 1024*1024
  int c = idx >> 10, k = idx & 1023;
  int kk = k & 511;
  bool hi = k >= 512;
  float v;
  if (c < 512) v = hi ? -ld_in(wo_i, kk * 512 + c, fi) : ld_in(wo_r, kk * 512 + c, fr);
  else { int cc = c - 512; v = hi ? ld_in(wo_r, kk * 512 + cc, fr) : ld_in(wo_i, kk * 512 + cc, fi); }
  wot[idx] = (bf16)v;
}

// Xd [4096][1024]: cols [0,512)=x[...,0], [512,1024)=x[...,1]
__global__ __launch_bounds__(256) void k_build_xd(const void* __restrict__ x, bf16* __restrict__ xd,
                                                  const int* __restrict__ flags) {
  const int f = flags[0];
  int idx = blockIdx.x * 256 + threadIdx.x;
  int m = idx >> 10, k = idx & 1023;
  long long src = (k < 512) ? ((long long)m * 1024 + k * 2) : ((long long)m * 1024 + (k - 512) * 2 + 1);
  xd[idx] = (bf16)ld_in(x, src, f);
}

__global__ __launch_bounds__(256) void k_build_rel(const void* __restrict__ rel, bf16* __restrict__ rel_c,
                                                   const int* __restrict__ flags) {
  const int f = flags[9];
  int idx = blockIdx.x * 256 + threadIdx.x;
  if (idx < 65600) rel_c[idx] = (bf16)ld_in(rel, idx, f);
}

// -------------------- MFMA GEMM: C = A[M][K] @ Bt[N][K]^T (m97 structure) --------------------
// MODE 0: bf16 store. MODE 1: +bias, fp32 interleaved store (final output).
template <int MODE>
__global__ __launch_bounds__(256) void k_gemm(
    const bf16* __restrict__ A, const bf16* __restrict__ Bt,
    bf16* __restrict__ C, float* __restrict__ Cf,
    const int M, const int N, const int K,
    const void* __restrict__ bias_r, const void* __restrict__ bias_i,
    const int* __restrict__ flags) {
  __shared__ __align__(16) bf16 As[128 * 32];
  __shared__ __align__(16) bf16 Bs[128 * 32];
  const int tid = threadIdx.x;
  const int wave = tid >> 6, lane = tid & 63;
  const int lane15 = lane & 15, quad = lane >> 4;
  const int qk0 = quad * 8;
  const int bm = blockIdx.y * 128, bn = blockIdx.x * 128;
  const int wm = (wave >> 1) * 64, wn = (wave & 1) * 64;
  const int sr = tid >> 2;
  const int sc = (tid & 3) * 8;
  f32x4 acc[4][4];
#pragma unroll
  for (int i = 0; i < 4; ++i)
#pragma unroll
    for (int j = 0; j < 4; ++j) acc[i][j] = (f32x4){0.f, 0.f, 0.f, 0.f};

  for (int k0 = 0; k0 < K; k0 += 32) {
#pragma unroll
    for (int p = 0; p < 2; ++p) {
      const int r = p * 64 + sr;
      *(bf16x8*)(As + r * 32 + sc) = *(const bf16x8*)(A + (size_t)(bm + r) * K + k0 + sc);
      *(bf16x8*)(Bs + r * 32 + sc) = *(const bf16x8*)(Bt + (size_t)(bn + r) * K + k0 + sc);
    }
    __syncthreads();
    bf16x8 af[4], bfr[4];
#pragma unroll
    for (int mt = 0; mt < 4; ++mt) af[mt] = *(const bf16x8*)(As + (wm + mt * 16 + lane15) * 32 + qk0);
#pragma unroll
    for (int nt = 0; nt < 4; ++nt) bfr[nt] = *(const bf16x8*)(Bs + (wn + nt * 16 + lane15) * 32 + qk0);
#pragma unroll
    for (int mt = 0; mt < 4; ++mt)
#pragma unroll
      for (int nt = 0; nt < 4; ++nt) acc[mt][nt] = MFMA16(af[mt], bfr[nt], acc[mt][nt]);
    __syncthreads();
  }
  int fbr = 0, fbi = 0;
  if constexpr (MODE == 1) { fbr = flags[7]; fbi = flags[8]; }
#pragma unroll
  for (int mt = 0; mt < 4; ++mt)
#pragma unroll
    for (int nt = 0; nt < 4; ++nt)
#pragma unroll
      for (int r = 0; r < 4; ++r) {
        const int m = bm + wm + mt * 16 + quad * 4 + r;
        const int n = bn + wn + nt * 16 + lane15;
        float v = acc[mt][nt][r];
        if constexpr (MODE == 0) {
          C[(size_t)m * N + n] = (bf16)v;
        } else {
          const int c = (n < 512) ? n : n - 512;
          v += ld_in((n < 512) ? bias_r : bias_i, c, (n < 512) ? fbr : fbi);
          Cf[(size_t)m * 1024 + c * 2 + ((n < 512) ? 0 : 1)] = v;  // FP32 output
        }
      }
}

// -------------------- V transpose: Vt[bh][d][n] from C1 v-columns --------------------
__global__ __launch_bounds__(256) void k_vt(const bf16* __restrict__ C1,
                                            bf16* __restrict__ vt_r, bf16* __restrict__ vt_i) {
  __shared__ __align__(16) bf16 tr[64][72], ti[64][72];
  const int bid = blockIdx.x, tid = threadIdx.x;
  const int bh = bid >> 4, jt = bid & 15;
  const int b = bh >> 3, h = bh & 7;
  const int j0 = jt * 64;
#pragma unroll
  for (int p = 0; p < 2; ++p) {
    const int j = p * 32 + (tid >> 3);
    const int d0 = (tid & 7) * 8;
    const size_t base = (size_t)(b * 1024 + j0 + j) * 3072 + h * 64 + d0;
    *(bf16x8*)&tr[j][d0] = *(const bf16x8*)(C1 + base + 1536);  // vr cols
    *(bf16x8*)&ti[j][d0] = *(const bf16x8*)(C1 + base + 2560);  // vi cols
  }
  __syncthreads();
#pragma unroll
  for (int p = 0; p < 2; ++p) {
    const int d = p * 32 + (tid >> 3);
    const int jj0 = (tid & 7) * 8;
    bf16x8 vr, vi;
#pragma unroll
    for (int e = 0; e < 8; ++e) { vr[e] = tr[jj0 + e][d]; vi[e] = ti[jj0 + e][d]; }
    const size_t dst = (size_t)(bh * 64 + d) * 1024 + j0 + jj0;
    *(bf16x8*)(vt_r + dst) = vr;
    *(bf16x8*)(vt_i + dst) = vi;
  }
}

// -------------------- fused MFMA attention (verified round 3/4 bitwise) --------------------
__device__ __forceinline__ bf16x8 lds_frag72(const bf16* base, int row, int kofs) {
  return *(const bf16x8*)(base + row * 72 + kofs);
}

__global__ __launch_bounds__(256) void k_attn(
    const bf16* __restrict__ C1, const bf16* __restrict__ vt_r, const bf16* __restrict__ vt_i,
    const bf16* __restrict__ rel, bf16* __restrict__ Oc) {
  __shared__ __align__(16) bf16 kr_s[64 * 72];
  __shared__ __align__(16) bf16 ki_s[64 * 72];
  __shared__ __align__(16) bf16 vtr_s[64 * 72];
  __shared__ __align__(16) bf16 vti_s[64 * 72];
  __shared__ __align__(16) bf16 R_s[128 * 72];
  __shared__ __align__(16) bf16 Gr_s[4][16][80];
  __shared__ __align__(16) bf16 Gi_s[4][16][80];
  __shared__ __align__(16) bf16 P_s[4][16][72];

  const int tid = threadIdx.x;
  const int wave = tid >> 6, lane = tid & 63;
  const int lane15 = lane & 15, quad = lane >> 4;
  const int qk0 = quad * 8;
  const int bid = blockIdx.x;
  const int bh = bid >> 4, it = bid & 15;
  const int b = bh >> 3, h = bh & 7;
  const int i0 = it * 64;
  const int tq = tid >> 3;
  const int tc = (tid & 7) * 8;

  const size_t qbase = (size_t)(b * 1024 + i0 + wave * 16 + lane15) * 3072 + h * 64;
  bf16x8 aqr[2], aqi[2], aqin[2];
  aqr[0] = *(const bf16x8*)(C1 + qbase + qk0);
  aqr[1] = *(const bf16x8*)(C1 + qbase + 32 + qk0);
  aqi[0] = *(const bf16x8*)(C1 + qbase + 512 + qk0);
  aqi[1] = *(const bf16x8*)(C1 + qbase + 512 + 32 + qk0);
#pragma unroll
  for (int c = 0; c < 2; ++c)
#pragma unroll
    for (int e = 0; e < 8; ++e) aqin[c][e] = (bf16)(-(float)aqi[c][e]);

  f32x4 o_r[4], o_i[4];
#pragma unroll
  for (int dt = 0; dt < 4; ++dt) { o_r[dt] = (f32x4){0.f,0.f,0.f,0.f}; o_i[dt] = (f32x4){0.f,0.f,0.f,0.f}; }
  float m_st[4] = {0.f, 0.f, 0.f, 0.f}, l_st[4] = {0.f, 0.f, 0.f, 0.f};

  for (int jt = 0; jt < 16; ++jt) {
    const int j0 = jt * 64;
    const int t0 = 512 + i0 - j0 - 63;
#pragma unroll
    for (int p = 0; p < 2; ++p) {
      const int row = p * 32 + tq;
      const size_t gbase = (size_t)(b * 1024 + j0 + row) * 3072 + h * 64 + tc;
      *(bf16x8*)(kr_s + row * 72 + tc) = *(const bf16x8*)(C1 + gbase + 1024);
      *(bf16x8*)(ki_s + row * 72 + tc) = *(const bf16x8*)(C1 + gbase + 2048);
      const size_t vbase = (size_t)(bh * 64 + row) * 1024 + j0 + tc;
      *(bf16x8*)(vtr_s + row * 72 + tc) = *(const bf16x8*)(vt_r + vbase);
      *(bf16x8*)(vti_s + row * 72 + tc) = *(const bf16x8*)(vt_i + vbase);
    }
#pragma unroll
    for (int p = 0; p < 4; ++p) {
      const int row = p * 32 + tq;
      int trw = t0 + row;
      trw = trw < 0 ? 0 : (trw > 1024 ? 1024 : trw);
      *(bf16x8*)(R_s + row * 72 + tc) = *(const bf16x8*)(rel + (size_t)trw * 64 + tc);
    }
    __syncthreads();

    f32x4 s_r[4], s_i[4];
#pragma unroll
    for (int ct = 0; ct < 4; ++ct) { s_r[ct] = (f32x4){0.f,0.f,0.f,0.f}; s_i[ct] = (f32x4){0.f,0.f,0.f,0.f}; }
#pragma unroll
    for (int ct = 0; ct < 4; ++ct) {
      const int krow = ct * 16 + lane15;
      bf16x8 bkr0 = lds_frag72(kr_s, krow, qk0), bkr1 = lds_frag72(kr_s, krow, 32 + qk0);
      bf16x8 bki0 = lds_frag72(ki_s, krow, qk0), bki1 = lds_frag72(ki_s, krow, 32 + qk0);
      s_r[ct] = MFMA16(aqr[0], bkr0, s_r[ct]);
      s_r[ct] = MFMA16(aqr[1], bkr1, s_r[ct]);
      s_r[ct] = MFMA16(aqin[0], bki0, s_r[ct]);
      s_r[ct] = MFMA16(aqin[1], bki1, s_r[ct]);
      s_i[ct] = MFMA16(aqr[0], bki0, s_i[ct]);
      s_i[ct] = MFMA16(aqr[1], bki1, s_i[ct]);
      s_i[ct] = MFMA16(aqi[0], bkr0, s_i[ct]);
      s_i[ct] = MFMA16(aqi[1], bkr1, s_i[ct]);
    }
#pragma unroll
    for (int g = 0; g < 5; ++g) {
      const int rrow = (wave + g) * 16 + lane15;
      bf16x8 br0 = lds_frag72(R_s, rrow, qk0), br1 = lds_frag72(R_s, rrow, 32 + qk0);
      f32x4 gr = (f32x4){0.f,0.f,0.f,0.f}, gi = (f32x4){0.f,0.f,0.f,0.f};
      gr = MFMA16(aqr[0], br0, gr);
      gr = MFMA16(aqr[1], br1, gr);
      gi = MFMA16(aqi[0], br0, gi);
      gi = MFMA16(aqi[1], br1, gi);
#pragma unroll
      for (int r = 0; r < 4; ++r) {
        Gr_s[wave][quad * 4 + r][g * 16 + lane15] = (bf16)gr[r];
        Gi_s[wave][quad * 4 + r][g * 16 + lane15] = (bf16)gi[r];
      }
    }
    __syncthreads();

    float mag[4][4];
#pragma unroll
    for (int ct = 0; ct < 4; ++ct) {
      const int jj = ct * 16 + lane15;
#pragma unroll
      for (int r = 0; r < 4; ++r) {
        const int ii = quad * 4 + r;
        const float gr = (float)Gr_s[wave][ii][ii - jj + 63];
        const float gi = (float)Gi_s[wave][ii][ii - jj + 63];
        const float dr = 0.125f * (s_r[ct][r] + gr);
        const float di = 0.125f * (s_i[ct][r] + gi);
        mag[ct][r] = sqrtf(dr * dr + di * di);
      }
    }
    float alpha[4];
#pragma unroll
    for (int r = 0; r < 4; ++r) {
      float v = fmaxf(fmaxf(mag[0][r], mag[1][r]), fmaxf(mag[2][r], mag[3][r]));
#pragma unroll
      for (int s = 1; s < 16; s <<= 1) v = fmaxf(v, __shfl_xor(v, s, 64));
      const float mn = fmaxf(m_st[r], v);
      alpha[r] = __expf(m_st[r] - mn);
      m_st[r] = mn;
    }
    float rowsum[4] = {0.f, 0.f, 0.f, 0.f};
#pragma unroll
    for (int ct = 0; ct < 4; ++ct)
#pragma unroll
      for (int r = 0; r < 4; ++r) {
        const float p = __expf(mag[ct][r] - m_st[r]);
        rowsum[r] += p;
        P_s[wave][quad * 4 + r][ct * 16 + lane15] = (bf16)p;
      }
#pragma unroll
    for (int r = 0; r < 4; ++r) {
      float v = rowsum[r];
#pragma unroll
      for (int s = 1; s < 16; s <<= 1) v += __shfl_xor(v, s, 64);
      l_st[r] = l_st[r] * alpha[r] + v;
#pragma unroll
      for (int dt = 0; dt < 4; ++dt) { o_r[dt][r] *= alpha[r]; o_i[dt][r] *= alpha[r]; }
    }

    bf16x8 ap0 = *(const bf16x8*)&P_s[wave][lane15][qk0];
    bf16x8 ap1 = *(const bf16x8*)&P_s[wave][lane15][32 + qk0];
#pragma unroll
    for (int dt = 0; dt < 4; ++dt) {
      const int vrow = dt * 16 + lane15;
      bf16x8 bv0 = lds_frag72(vtr_s, vrow, qk0), bv1 = lds_frag72(vtr_s, vrow, 32 + qk0);
      o_r[dt] = MFMA16(ap0, bv0, o_r[dt]);
      o_r[dt] = MFMA16(ap1, bv1, o_r[dt]);
      bv0 = lds_frag72(vti_s, vrow, qk0);
      bv1 = lds_frag72(vti_s, vrow, 32 + qk0);
      o_i[dt] = MFMA16(ap0, bv0, o_i[dt]);
      o_i[dt] = MFMA16(ap1, bv1, o_i[dt]);
    }
    __syncthreads();
  }

  const size_t obase = (size_t)(b * 1024 + i0 + wave * 16) * 1024 + h * 64;
#pragma unroll
  for (int r = 0; r < 4; ++r) {
    const float inv = 1.0f / l_st[r];
    const int ii = quad * 4 + r;
#pragma unroll
    for (int dt = 0; dt < 4; ++dt) {
      Oc[obase + (size_t)ii * 1024 + dt * 16 + lane15] = (bf16)(o_r[dt][r] * inv);
      Oc[obase + (size_t)ii * 1024 + 512 + dt * 16 + lane15] = (bf16)(o_i[dt][r] * inv);
    }
  }
}

// -------------------- launch --------------------
extern "C" void kernel_launch(void* const* d_in, const int* in_sizes, int n_in,
                              void* d_out, int out_size, void* d_ws, size_t ws_size,
                              hipStream_t stream) {
  float* out = (float*)d_out;

  if (n_in != 10) { k_diag<<<16384, 256, 0, stream>>>(out, 300000.f); return; }
  if (out_size != 4194304) { k_diag<<<16384, 256, 0, stream>>>(out, 400000.f); return; }
  static const int dict_sizes[10] = {4194304, 262144, 262144, 524288, 524288,
                                     262144, 262144, 512, 512, 65600};
  for (int i = 0; i < 10; ++i) {
    if (in_sizes[i] != dict_sizes[i]) { k_diag<<<16384, 256, 0, stream>>>(out, 200000.f); return; }
  }
  const size_t NEED = 50462888;
  if (ws_size < NEED) { k_diag<<<16384, 256, 0, stream>>>(out, 100000.f); return; }

  const void* x     = d_in[0];
  const void* wq_r  = d_in[1];
  const void* wq_i  = d_in[2];
  const void* wkv_r = d_in[3];
  const void* wkv_i = d_in[4];
  const void* wo_r  = d_in[5];
  const void* wo_i  = d_in[6];
  const void* bo_r  = d_in[7];
  const void* bo_i  = d_in[8];
  const void* rel   = d_in[9];

  char* ws = (char*)d_ws;
  bf16* C1   = (bf16*)(ws);                // [4096][3072]  24 MB
  bf16* Xd   = (bf16*)(ws + 25165824);     // [4096][1024]   8 MB (dead after gemm0)
  bf16* Vtr  = (bf16*)(ws + 25165824);     //   -> reused: [32][64][1024] 4 MB
  bf16* Vti  = (bf16*)(ws + 29360128);     //   -> reused: 4 MB
  bf16* Oc   = (bf16*)(ws + 33554432);     // [4096][1024]   8 MB
  bf16* WcT  = (bf16*)(ws + 41943040);     // [3072][1024]   6 MB
  bf16* WoT  = (bf16*)(ws + 48234496);     // [1024][1024]   2 MB
  bf16* relc = (bf16*)(ws + 50331648);     // [1025][64]   131200 B
  int*  flags= (int*)(ws + 50462848);      // 10 ints -> end 50462888

  const void* logical[10] = {x, wq_r, wq_i, wkv_r, wkv_i, wo_r, wo_i, bo_r, bo_i, rel};
  for (int i = 0; i < 10; ++i) {
    int nhalf = dict_sizes[i] < 65536 ? dict_sizes[i] : 65536;
    k_detect_one<<<1, 256, 0, stream>>>((const unsigned short*)logical[i], nhalf, flags + i);
  }

  k_build_wct<<<12288, 256, 0, stream>>>(wq_r, wq_i, wkv_r, wkv_i, WcT, flags);
  k_build_wot<<<4096, 256, 0, stream>>>(wo_r, wo_i, WoT, flags);
  k_build_xd<<<16384, 256, 0, stream>>>(x, Xd, flags);
  k_build_rel<<<257, 256, 0, stream>>>(rel, relc, flags);

  k_gemm<0><<<dim3(24, 32), 256, 0, stream>>>(Xd, WcT, C1, nullptr, 4096, 3072, 1024,
                                              nullptr, nullptr, flags);
  k_vt<<<512, 256, 0, stream>>>(C1, Vtr, Vti);
  k_attn<<<512, 256, 0, stream>>>(C1, Vtr, Vti, relc, Oc);
  k_gemm<1><<<dim3(8, 32), 256, 0, stream>>>(Oc, WoT, nullptr, out, 4096, 1024, 1024,
                                             bo_r, bo_i, flags);
}

// Round 12
// 362.525 us; speedup vs baseline: 25.3811x; 1.8645x over previous
//
#include <hip/hip_runtime.h>
#include <hip/hip_bf16.h>

// b=4, n=1024, dim=512, heads=8, dhead=64, inner=512, MAX_POS=512.
// Inputs fp32 (flag-detected, robust to bf16). OUTPUT = FP32.
// ROUND 12: (1) k_attn LDS 85->74 KB (P aliased into Gr buffer) + dropped
// wave-private mid barrier -> 2 blocks/CU; (2) GEMM staging via
// global_load_lds width-16 (m97 verified pattern); (3) single merged
// dtype-detector launch.

using bf16 = __bf16;
typedef __bf16 bf16x8 __attribute__((ext_vector_type(8)));
typedef float f32x4 __attribute__((ext_vector_type(4)));

#define MFMA16(a, b, c) __builtin_amdgcn_mfma_f32_16x16x32_bf16((a), (b), (c), 0, 0, 0)

__device__ __forceinline__ float ld_in(const void* p, long long i, int f32) {
  return f32 ? ((const float*)p)[i] : (float)((const bf16*)p)[i];
}

// async global->LDS, 16B/lane; LDS dest = wave-uniform base + lane*16 (m97)
__device__ __forceinline__ void gl_lds16(const bf16* g, const bf16* l) {
  __builtin_amdgcn_global_load_lds(
      (const __attribute__((address_space(1))) void*)(unsigned long long)g,
      (__attribute__((address_space(3))) void*)(unsigned int)(unsigned long long)l,
      16, 0, 0);
}

__global__ __launch_bounds__(256) void k_diag(float* __restrict__ out, float v) {
  int idx = blockIdx.x * 256 + threadIdx.x;
  if (idx < 4194304) out[idx] = v;
}

// merged per-input dtype detector: blockIdx.x = logical input index
__global__ void k_detect_all(
    const unsigned short* p0, const unsigned short* p1, const unsigned short* p2,
    const unsigned short* p3, const unsigned short* p4, const unsigned short* p5,
    const unsigned short* p6, const unsigned short* p7, const unsigned short* p8,
    const unsigned short* p9, int* __restrict__ flags) {
  static const int sizes[10] = {65536, 65536, 65536, 65536, 65536,
                                65536, 65536, 512, 512, 65536};
  const unsigned short* ptrs[10] = {p0, p1, p2, p3, p4, p5, p6, p7, p8, p9};
  __shared__ int cnt;
  if (threadIdx.x == 0) cnt = 0;
  __syncthreads();
  const int which = blockIdx.x;
  const unsigned short* p = ptrs[which];
  const int nhalf = sizes[which];
  int c = 0;
  for (int i = threadIdx.x; i < nhalf; i += 256) {
    const unsigned u = p[i];
    const unsigned e = (u >> 7) & 0xFF;
    if (e == 0xFF || (e < 64 && (u & 0x7FFF) != 0)) ++c;
  }
  atomicAdd(&cnt, c);
  __syncthreads();
  if (threadIdx.x == 0) flags[which] = (cnt > (nhalf >> 6)) ? 1 : 0;
}

// -------------------- prep: transposed (N-major) weight operands --------------------
__global__ __launch_bounds__(256) void k_build_wct(
    const void* __restrict__ wq_r, const void* __restrict__ wq_i,
    const void* __restrict__ wkv_r, const void* __restrict__ wkv_i,
    bf16* __restrict__ wct, const int* __restrict__ flags) {
  const int fqr = flags[1], fqi = flags[2], fkr = flags[3], fki = flags[4];
  int idx = blockIdx.x * 256 + threadIdx.x;  // 3072*1024
  int c = idx >> 10, k = idx & 1023;
  int kk = k & 511;
  bool hi = k >= 512;
  float v;
  if (c < 512)        v = hi ? -ld_in(wq_i, kk * 512 + c, fqi) : ld_in(wq_r, kk * 512 + c, fqr);
  else if (c < 1024)  { int cc = c - 512;  v = hi ? ld_in(wq_r, kk * 512 + cc, fqr)  : ld_in(wq_i, kk * 512 + cc, fqi); }
  else if (c < 2048)  { int cc = c - 1024; v = hi ? -ld_in(wkv_i, kk * 1024 + cc, fki) : ld_in(wkv_r, kk * 1024 + cc, fkr); }
  else                { int cc = c - 2048; v = hi ? ld_in(wkv_r, kk * 1024 + cc, fkr) : ld_in(wkv_i, kk * 1024 + cc, fki); }
  wct[idx] = (bf16)v;
}

__global__ __launch_bounds__(256) void k_build_wot(
    const void* __restrict__ wo_r, const void* __restrict__ wo_i,
    bf16* __restrict__ wot, const int* __restrict__ flags) {
  const int fr = flags[5], fi = flags[6];
  int idx = blockIdx.x * 256 + threadIdx.x;  // 1024*1024
  int c = idx >> 10, k = idx & 1023;
  int kk = k & 511;
  bool hi = k >= 512;
  float v;
  if (c < 512) v = hi ? -ld_in(wo_i, kk * 512 + c, fi) : ld_in(wo_r, kk * 512 + c, fr);
  else { int cc = c - 512; v = hi ? ld_in(wo_r, kk * 512 + cc, fr) : ld_in(wo_i, kk * 512 + cc, fi); }
  wot[idx] = (bf16)v;
}

__global__ __launch_bounds__(256) void k_build_xd(const void* __restrict__ x, bf16* __restrict__ xd,
                                                  const int* __restrict__ flags) {
  const int f = flags[0];
  int idx = blockIdx.x * 256 + threadIdx.x;
  int m = idx >> 10, k = idx & 1023;
  long long src = (k < 512) ? ((long long)m * 1024 + k * 2) : ((long long)m * 1024 + (k - 512) * 2 + 1);
  xd[idx] = (bf16)ld_in(x, src, f);
}

__global__ __launch_bounds__(256) void k_build_rel(const void* __restrict__ rel, bf16* __restrict__ rel_c,
                                                   const int* __restrict__ flags) {
  const int f = flags[9];
  int idx = blockIdx.x * 256 + threadIdx.x;
  if (idx < 65600) rel_c[idx] = (bf16)ld_in(rel, idx, f);
}

// -------------------- MFMA GEMM (m97: global_load_lds staging) --------------------
// MODE 0: bf16 store. MODE 1: +bias, fp32 interleaved store (final output).
template <int MODE>
__global__ __launch_bounds__(256) void k_gemm(
    const bf16* __restrict__ A, const bf16* __restrict__ Bt,
    bf16* __restrict__ C, float* __restrict__ Cf,
    const int M, const int N, const int K,
    const void* __restrict__ bias_r, const void* __restrict__ bias_i,
    const int* __restrict__ flags) {
  __shared__ __align__(16) bf16 As[128 * 32];
  __shared__ __align__(16) bf16 Bs[128 * 32];
  const int tid = threadIdx.x;
  const int wave = tid >> 6, lane = tid & 63;
  const int lane15 = lane & 15, quad = lane >> 4;
  const int qk0 = quad * 8;
  const int bm = blockIdx.y * 128, bn = blockIdx.x * 128;
  const int wm = (wave >> 1) * 64, wn = (wave & 1) * 64;
  const int sr = lane >> 2;         // 16 rows per wave-issue (4 lanes x 16B per 64B row)
  const int sc = (lane & 3) * 8;
  f32x4 acc[4][4];
#pragma unroll
  for (int i = 0; i < 4; ++i)
#pragma unroll
    for (int j = 0; j < 4; ++j) acc[i][j] = (f32x4){0.f, 0.f, 0.f, 0.f};

  for (int k0 = 0; k0 < K; k0 += 32) {
#pragma unroll
    for (int p = 0; p < 2; ++p) {
      const int r0 = p * 64 + wave * 16;
      gl_lds16(A + (size_t)(bm + r0 + sr) * K + k0 + sc, As + r0 * 32);
      gl_lds16(Bt + (size_t)(bn + r0 + sr) * K + k0 + sc, Bs + r0 * 32);
    }
    __syncthreads();
    bf16x8 af[4], bfr[4];
#pragma unroll
    for (int mt = 0; mt < 4; ++mt) af[mt] = *(const bf16x8*)(As + (wm + mt * 16 + lane15) * 32 + qk0);
#pragma unroll
    for (int nt = 0; nt < 4; ++nt) bfr[nt] = *(const bf16x8*)(Bs + (wn + nt * 16 + lane15) * 32 + qk0);
#pragma unroll
    for (int mt = 0; mt < 4; ++mt)
#pragma unroll
      for (int nt = 0; nt < 4; ++nt) acc[mt][nt] = MFMA16(af[mt], bfr[nt], acc[mt][nt]);
    __syncthreads();
  }
  int fbr = 0, fbi = 0;
  if constexpr (MODE == 1) { fbr = flags[7]; fbi = flags[8]; }
#pragma unroll
  for (int mt = 0; mt < 4; ++mt)
#pragma unroll
    for (int nt = 0; nt < 4; ++nt)
#pragma unroll
      for (int r = 0; r < 4; ++r) {
        const int m = bm + wm + mt * 16 + quad * 4 + r;
        const int n = bn + wn + nt * 16 + lane15;
        float v = acc[mt][nt][r];
        if constexpr (MODE == 0) {
          C[(size_t)m * N + n] = (bf16)v;
        } else {
          const int c = (n < 512) ? n : n - 512;
          v += ld_in((n < 512) ? bias_r : bias_i, c, (n < 512) ? fbr : fbi);
          Cf[(size_t)m * 1024 + c * 2 + ((n < 512) ? 0 : 1)] = v;  // FP32 output
        }
      }
}

// -------------------- V transpose --------------------
__global__ __launch_bounds__(256) void k_vt(const bf16* __restrict__ C1,
                                            bf16* __restrict__ vt_r, bf16* __restrict__ vt_i) {
  __shared__ __align__(16) bf16 tr[64][72], ti[64][72];
  const int bid = blockIdx.x, tid = threadIdx.x;
  const int bh = bid >> 4, jt = bid & 15;
  const int b = bh >> 3, h = bh & 7;
  const int j0 = jt * 64;
#pragma unroll
  for (int p = 0; p < 2; ++p) {
    const int j = p * 32 + (tid >> 3);
    const int d0 = (tid & 7) * 8;
    const size_t base = (size_t)(b * 1024 + j0 + j) * 3072 + h * 64 + d0;
    *(bf16x8*)&tr[j][d0] = *(const bf16x8*)(C1 + base + 1536);
    *(bf16x8*)&ti[j][d0] = *(const bf16x8*)(C1 + base + 2560);
  }
  __syncthreads();
#pragma unroll
  for (int p = 0; p < 2; ++p) {
    const int d = p * 32 + (tid >> 3);
    const int jj0 = (tid & 7) * 8;
    bf16x8 vr, vi;
#pragma unroll
    for (int e = 0; e < 8; ++e) { vr[e] = tr[jj0 + e][d]; vi[e] = ti[jj0 + e][d]; }
    const size_t dst = (size_t)(bh * 64 + d) * 1024 + j0 + jj0;
    *(bf16x8*)(vt_r + dst) = vr;
    *(bf16x8*)(vt_i + dst) = vi;
  }
}

// -------------------- fused MFMA attention --------------------
__device__ __forceinline__ bf16x8 lds_frag72(const bf16* base, int row, int kofs) {
  return *(const bf16x8*)(base + row * 72 + kofs);
}

__global__ __launch_bounds__(256, 2) void k_attn(
    const bf16* __restrict__ C1, const bf16* __restrict__ vt_r, const bf16* __restrict__ vt_i,
    const bf16* __restrict__ rel, bf16* __restrict__ Oc) {
  __shared__ __align__(16) bf16 kr_s[64 * 72];
  __shared__ __align__(16) bf16 ki_s[64 * 72];
  __shared__ __align__(16) bf16 vtr_s[64 * 72];
  __shared__ __align__(16) bf16 vti_s[64 * 72];
  __shared__ __align__(16) bf16 R_s[128 * 72];
  __shared__ __align__(16) bf16 GP_s[4][16][80];  // G-real, then reused for P
  __shared__ __align__(16) bf16 Gi_s[4][16][80];
  // total LDS = 4*9216 + 18432 + 2*10240 = 75776 B -> 2 blocks/CU

  const int tid = threadIdx.x;
  const int wave = tid >> 6, lane = tid & 63;
  const int lane15 = lane & 15, quad = lane >> 4;
  const int qk0 = quad * 8;
  const int bid = blockIdx.x;
  const int bh = bid >> 4, it = bid & 15;
  const int b = bh >> 3, h = bh & 7;
  const int i0 = it * 64;
  const int tq = tid >> 3;
  const int tc = (tid & 7) * 8;

  const size_t qbase = (size_t)(b * 1024 + i0 + wave * 16 + lane15) * 3072 + h * 64;
  bf16x8 aqr[2], aqi[2], aqin[2];
  aqr[0] = *(const bf16x8*)(C1 + qbase + qk0);
  aqr[1] = *(const bf16x8*)(C1 + qbase + 32 + qk0);
  aqi[0] = *(const bf16x8*)(C1 + qbase + 512 + qk0);
  aqi[1] = *(const bf16x8*)(C1 + qbase + 512 + 32 + qk0);
#pragma unroll
  for (int c = 0; c < 2; ++c)
#pragma unroll
    for (int e = 0; e < 8; ++e) aqin[c][e] = (bf16)(-(float)aqi[c][e]);

  f32x4 o_r[4], o_i[4];
#pragma unroll
  for (int dt = 0; dt < 4; ++dt) { o_r[dt] = (f32x4){0.f,0.f,0.f,0.f}; o_i[dt] = (f32x4){0.f,0.f,0.f,0.f}; }
  float m_st[4] = {0.f, 0.f, 0.f, 0.f}, l_st[4] = {0.f, 0.f, 0.f, 0.f};

  for (int jt = 0; jt < 16; ++jt) {
    const int j0 = jt * 64;
    const int t0 = 512 + i0 - j0 - 63;
#pragma unroll
    for (int p = 0; p < 2; ++p) {
      const int row = p * 32 + tq;
      const size_t gbase = (size_t)(b * 1024 + j0 + row) * 3072 + h * 64 + tc;
      *(bf16x8*)(kr_s + row * 72 + tc) = *(const bf16x8*)(C1 + gbase + 1024);
      *(bf16x8*)(ki_s + row * 72 + tc) = *(const bf16x8*)(C1 + gbase + 2048);
      const size_t vbase = (size_t)(bh * 64 + row) * 1024 + j0 + tc;
      *(bf16x8*)(vtr_s + row * 72 + tc) = *(const bf16x8*)(vt_r + vbase);
      *(bf16x8*)(vti_s + row * 72 + tc) = *(const bf16x8*)(vt_i + vbase);
    }
#pragma unroll
    for (int p = 0; p < 4; ++p) {
      const int row = p * 32 + tq;
      int trw = t0 + row;
      trw = trw < 0 ? 0 : (trw > 1024 ? 1024 : trw);
      *(bf16x8*)(R_s + row * 72 + tc) = *(const bf16x8*)(rel + (size_t)trw * 64 + tc);
    }
    __syncthreads();

    // ---- scores ----
    f32x4 s_r[4], s_i[4];
#pragma unroll
    for (int ct = 0; ct < 4; ++ct) { s_r[ct] = (f32x4){0.f,0.f,0.f,0.f}; s_i[ct] = (f32x4){0.f,0.f,0.f,0.f}; }
#pragma unroll
    for (int ct = 0; ct < 4; ++ct) {
      const int krow = ct * 16 + lane15;
      bf16x8 bkr0 = lds_frag72(kr_s, krow, qk0), bkr1 = lds_frag72(kr_s, krow, 32 + qk0);
      bf16x8 bki0 = lds_frag72(ki_s, krow, qk0), bki1 = lds_frag72(ki_s, krow, 32 + qk0);
      s_r[ct] = MFMA16(aqr[0], bkr0, s_r[ct]);
      s_r[ct] = MFMA16(aqr[1], bkr1, s_r[ct]);
      s_r[ct] = MFMA16(aqin[0], bki0, s_r[ct]);
      s_r[ct] = MFMA16(aqin[1], bki1, s_r[ct]);
      s_i[ct] = MFMA16(aqr[0], bki0, s_i[ct]);
      s_i[ct] = MFMA16(aqr[1], bki1, s_i[ct]);
      s_i[ct] = MFMA16(aqi[0], bkr0, s_i[ct]);
      s_i[ct] = MFMA16(aqi[1], bkr1, s_i[ct]);
    }
    // ---- rel term (wave-private G buffers; no barrier needed) ----
#pragma unroll
    for (int g = 0; g < 5; ++g) {
      const int rrow = (wave + g) * 16 + lane15;
      bf16x8 br0 = lds_frag72(R_s, rrow, qk0), br1 = lds_frag72(R_s, rrow, 32 + qk0);
      f32x4 gr = (f32x4){0.f,0.f,0.f,0.f}, gi = (f32x4){0.f,0.f,0.f,0.f};
      gr = MFMA16(aqr[0], br0, gr);
      gr = MFMA16(aqr[1], br1, gr);
      gi = MFMA16(aqi[0], br0, gi);
      gi = MFMA16(aqi[1], br1, gi);
#pragma unroll
      for (int r = 0; r < 4; ++r) {
        GP_s[wave][quad * 4 + r][g * 16 + lane15] = (bf16)gr[r];
        Gi_s[wave][quad * 4 + r][g * 16 + lane15] = (bf16)gi[r];
      }
    }

    // ---- gather rel (Toeplitz), magnitudes, online softmax ----
    float mag[4][4];
#pragma unroll
    for (int ct = 0; ct < 4; ++ct) {
      const int jj = ct * 16 + lane15;
#pragma unroll
      for (int r = 0; r < 4; ++r) {
        const int ii = quad * 4 + r;
        const float gr = (float)GP_s[wave][ii][ii - jj + 63];
        const float gi = (float)Gi_s[wave][ii][ii - jj + 63];
        const float dr = 0.125f * (s_r[ct][r] + gr);
        const float di = 0.125f * (s_i[ct][r] + gi);
        mag[ct][r] = sqrtf(dr * dr + di * di);
      }
    }
    float alpha[4];
#pragma unroll
    for (int r = 0; r < 4; ++r) {
      float v = fmaxf(fmaxf(mag[0][r], mag[1][r]), fmaxf(mag[2][r], mag[3][r]));
#pragma unroll
      for (int s = 1; s < 16; s <<= 1) v = fmaxf(v, __shfl_xor(v, s, 64));
      const float mn = fmaxf(m_st[r], v);
      alpha[r] = __expf(m_st[r] - mn);
      m_st[r] = mn;
    }
    // P overwrites the G-real buffer (fully consumed above; wave-private)
    float rowsum[4] = {0.f, 0.f, 0.f, 0.f};
#pragma unroll
    for (int ct = 0; ct < 4; ++ct)
#pragma unroll
      for (int r = 0; r < 4; ++r) {
        const float p = __expf(mag[ct][r] - m_st[r]);
        rowsum[r] += p;
        GP_s[wave][quad * 4 + r][ct * 16 + lane15] = (bf16)p;
      }
#pragma unroll
    for (int r = 0; r < 4; ++r) {
      float v = rowsum[r];
#pragma unroll
      for (int s = 1; s < 16; s <<= 1) v += __shfl_xor(v, s, 64);
      l_st[r] = l_st[r] * alpha[r] + v;
#pragma unroll
      for (int dt = 0; dt < 4; ++dt) { o_r[dt][r] *= alpha[r]; o_i[dt][r] *= alpha[r]; }
    }

    bf16x8 ap0 = *(const bf16x8*)&GP_s[wave][lane15][qk0];
    bf16x8 ap1 = *(const bf16x8*)&GP_s[wave][lane15][32 + qk0];
#pragma unroll
    for (int dt = 0; dt < 4; ++dt) {
      const int vrow = dt * 16 + lane15;
      bf16x8 bv0 = lds_frag72(vtr_s, vrow, qk0), bv1 = lds_frag72(vtr_s, vrow, 32 + qk0);
      o_r[dt] = MFMA16(ap0, bv0, o_r[dt]);
      o_r[dt] = MFMA16(ap1, bv1, o_r[dt]);
      bv0 = lds_frag72(vti_s, vrow, qk0);
      bv1 = lds_frag72(vti_s, vrow, 32 + qk0);
      o_i[dt] = MFMA16(ap0, bv0, o_i[dt]);
      o_i[dt] = MFMA16(ap1, bv1, o_i[dt]);
    }
    __syncthreads();
  }

  const size_t obase = (size_t)(b * 1024 + i0 + wave * 16) * 1024 + h * 64;
#pragma unroll
  for (int r = 0; r < 4; ++r) {
    const float inv = 1.0f / l_st[r];
    const int ii = quad * 4 + r;
#pragma unroll
    for (int dt = 0; dt < 4; ++dt) {
      Oc[obase + (size_t)ii * 1024 + dt * 16 + lane15] = (bf16)(o_r[dt][r] * inv);
      Oc[obase + (size_t)ii * 1024 + 512 + dt * 16 + lane15] = (bf16)(o_i[dt][r] * inv);
    }
  }
}

// -------------------- launch --------------------
extern "C" void kernel_launch(void* const* d_in, const int* in_sizes, int n_in,
                              void* d_out, int out_size, void* d_ws, size_t ws_size,
                              hipStream_t stream) {
  float* out = (float*)d_out;

  if (n_in != 10) { k_diag<<<16384, 256, 0, stream>>>(out, 300000.f); return; }
  if (out_size != 4194304) { k_diag<<<16384, 256, 0, stream>>>(out, 400000.f); return; }
  static const int dict_sizes[10] = {4194304, 262144, 262144, 524288, 524288,
                                     262144, 262144, 512, 512, 65600};
  for (int i = 0; i < 10; ++i) {
    if (in_sizes[i] != dict_sizes[i]) { k_diag<<<16384, 256, 0, stream>>>(out, 200000.f); return; }
  }
  const size_t NEED = 50462888;
  if (ws_size < NEED) { k_diag<<<16384, 256, 0, stream>>>(out, 100000.f); return; }

  const void* x     = d_in[0];
  const void* wq_r  = d_in[1];
  const void* wq_i  = d_in[2];
  const void* wkv_r = d_in[3];
  const void* wkv_i = d_in[4];
  const void* wo_r  = d_in[5];
  const void* wo_i  = d_in[6];
  const void* bo_r  = d_in[7];
  const void* bo_i  = d_in[8];
  const void* rel   = d_in[9];

  char* ws = (char*)d_ws;
  bf16* C1   = (bf16*)(ws);                // [4096][3072]  24 MB
  bf16* Xd   = (bf16*)(ws + 25165824);     // [4096][1024]   8 MB (dead after gemm0)
  bf16* Vtr  = (bf16*)(ws + 25165824);     //   -> reused 4 MB
  bf16* Vti  = (bf16*)(ws + 29360128);     //   -> reused 4 MB
  bf16* Oc   = (bf16*)(ws + 33554432);     // [4096][1024]   8 MB
  bf16* WcT  = (bf16*)(ws + 41943040);     // [3072][1024]   6 MB
  bf16* WoT  = (bf16*)(ws + 48234496);     // [1024][1024]   2 MB
  bf16* relc = (bf16*)(ws + 50331648);     // [1025][64]   131200 B
  int*  flags= (int*)(ws + 50462848);      // 10 ints

  k_detect_all<<<10, 256, 0, stream>>>(
      (const unsigned short*)x, (const unsigned short*)wq_r, (const unsigned short*)wq_i,
      (const unsigned short*)wkv_r, (const unsigned short*)wkv_i, (const unsigned short*)wo_r,
      (const unsigned short*)wo_i, (const unsigned short*)bo_r, (const unsigned short*)bo_i,
      (const unsigned short*)rel, flags);

  k_build_wct<<<12288, 256, 0, stream>>>(wq_r, wq_i, wkv_r, wkv_i, WcT, flags);
  k_build_wot<<<4096, 256, 0, stream>>>(wo_r, wo_i, WoT, flags);
  k_build_xd<<<16384, 256, 0, stream>>>(x, Xd, flags);
  k_build_rel<<<257, 256, 0, stream>>>(rel, relc, flags);

  k_gemm<0><<<dim3(24, 32), 256, 0, stream>>>(Xd, WcT, C1, nullptr, 4096, 3072, 1024,
                                              nullptr, nullptr, flags);
  k_vt<<<512, 256, 0, stream>>>(C1, Vtr, Vti);
  k_attn<<<512, 256, 0, stream>>>(C1, Vtr, Vti, relc, Oc);
  k_gemm<1><<<dim3(8, 32), 256, 0, stream>>>(Oc, WoT, nullptr, out, 4096, 1024, 1024,
                                             bo_r, bo_i, flags);
}